// Round 1
// baseline (428.850 us; speedup 1.0000x reference)
//
#include <hip/hip_runtime.h>
#include <stdint.h>

#define B_ 16
#define N_ 1024
#define C_ 256

typedef __attribute__((ext_vector_type(8))) short short8;
typedef __attribute__((ext_vector_type(4))) float f32x4;

__device__ __forceinline__ short f2bf(float f) {
  uint32_t u = __builtin_bit_cast(uint32_t, f);
  u += 0x7fffu + ((u >> 16) & 1u);   // RNE to bf16
  return (short)(u >> 16);
}

__device__ __forceinline__ short8 cvt8(const float* __restrict__ p) {
  float4 a = ((const float4*)p)[0];
  float4 b = ((const float4*)p)[1];
  short8 r;
  r[0] = f2bf(a.x); r[1] = f2bf(a.y); r[2] = f2bf(a.z); r[3] = f2bf(a.w);
  r[4] = f2bf(b.x); r[5] = f2bf(b.y); r[6] = f2bf(b.z); r[7] = f2bf(b.w);
  return r;
}

// V (B,N,C) f32  ->  Vt (B,C,N) bf16
__global__ __launch_bounds__(256) void vt_kernel(const float* __restrict__ V,
                                                 short* __restrict__ Vt) {
  __shared__ float tile[32][33];
  int b = blockIdx.z;
  int nb = blockIdx.x * 32;
  int cb = blockIdx.y * 32;
  int tx = threadIdx.x & 31;
  int ty = threadIdx.x >> 5;  // 0..7
#pragma unroll
  for (int i = 0; i < 32; i += 8)
    tile[ty + i][tx] = V[((size_t)b * N_ + nb + ty + i) * C_ + cb + tx];
  __syncthreads();
#pragma unroll
  for (int i = 0; i < 32; i += 8)
    Vt[((size_t)b * C_ + cb + ty + i) * N_ + nb + tx] = f2bf(tile[tx][ty + i]);
}

// S = mask ? -inf : (Q K^T + dis) / 16   written into p_attn region (raw scores)
__global__ __launch_bounds__(256) void qk_kernel(const float* __restrict__ Q,
                                                 const float* __restrict__ Km,
                                                 const float* __restrict__ dis,
                                                 const int* __restrict__ mask,
                                                 float* __restrict__ S) {
  int b = blockIdx.z;
  int qb = blockIdx.x * 64;
  int kb = blockIdx.y * 64;
  int tid = threadIdx.x;
  int w = tid >> 6;
  int lane = tid & 63;
  int l15 = lane & 15;
  int quad = lane >> 4;

  const float* Qp = Q + ((size_t)b * N_ + qb + w * 16 + l15) * C_ + quad * 8;
  const float* Kp = Km + ((size_t)b * N_ + kb + l15) * C_ + quad * 8;

  f32x4 z = {0.f, 0.f, 0.f, 0.f};
  f32x4 acc[4] = {z, z, z, z};

#pragma unroll
  for (int cs = 0; cs < C_; cs += 32) {
    short8 a  = cvt8(Qp + cs);
    short8 b0 = cvt8(Kp + cs);
    short8 b1 = cvt8(Kp + 16 * C_ + cs);
    short8 b2 = cvt8(Kp + 32 * C_ + cs);
    short8 b3 = cvt8(Kp + 48 * C_ + cs);
    acc[0] = __builtin_amdgcn_mfma_f32_16x16x32_bf16(a, b0, acc[0], 0, 0, 0);
    acc[1] = __builtin_amdgcn_mfma_f32_16x16x32_bf16(a, b1, acc[1], 0, 0, 0);
    acc[2] = __builtin_amdgcn_mfma_f32_16x16x32_bf16(a, b2, acc[2], 0, 0, 0);
    acc[3] = __builtin_amdgcn_mfma_f32_16x16x32_bf16(a, b3, acc[3], 0, 0, 0);
  }

  int q0 = qb + w * 16 + quad * 4;
#pragma unroll
  for (int t = 0; t < 4; t++) {
    int k = kb + t * 16 + l15;
#pragma unroll
    for (int r = 0; r < 4; r++) {
      size_t idx = ((size_t)b * N_ + q0 + r) * N_ + k;
      float sv = (acc[t][r] + dis[idx]) * 0.0625f;
      S[idx] = mask[idx] ? -__builtin_inff() : sv;
    }
  }
}

// row softmax in place (f32) + bf16 copy for the PV GEMM
__global__ __launch_bounds__(256) void softmax_kernel(float* __restrict__ P,
                                                      short* __restrict__ Pbf) {
  size_t row = blockIdx.x;
  float* S = P + row * N_;
  short* Pb = Pbf + row * N_;
  int tid = threadIdx.x;

  float4 v = ((float4*)S)[tid];
  float m = fmaxf(fmaxf(v.x, v.y), fmaxf(v.z, v.w));
#pragma unroll
  for (int off = 32; off; off >>= 1) m = fmaxf(m, __shfl_xor(m, off));

  __shared__ float redm[4], reds[4];
  int wv = tid >> 6;
  if ((tid & 63) == 0) redm[wv] = m;
  __syncthreads();
  m = fmaxf(fmaxf(redm[0], redm[1]), fmaxf(redm[2], redm[3]));

  float4 e;
  e.x = __expf(v.x - m);   // -inf -> 0
  e.y = __expf(v.y - m);
  e.z = __expf(v.z - m);
  e.w = __expf(v.w - m);
  float s = (e.x + e.y) + (e.z + e.w);
#pragma unroll
  for (int off = 32; off; off >>= 1) s += __shfl_xor(s, off);
  if ((tid & 63) == 0) reds[wv] = s;
  __syncthreads();
  s = (reds[0] + reds[1]) + (reds[2] + reds[3]);

  float inv = 1.0f / s;
  e.x *= inv; e.y *= inv; e.z *= inv; e.w *= inv;
  ((float4*)S)[tid] = e;
  short4 o;
  o.x = f2bf(e.x); o.y = f2bf(e.y); o.z = f2bf(e.z); o.w = f2bf(e.w);
  ((short4*)Pb)[tid] = o;
}

// p_val = P @ V   (A = P bf16, B-frags contiguous from Vt)
__global__ __launch_bounds__(256) void pv_kernel(const short* __restrict__ Pbf,
                                                 const short* __restrict__ Vt,
                                                 float* __restrict__ O) {
  int b = blockIdx.z;
  int qb = blockIdx.x * 64;
  int cb = blockIdx.y * 64;
  int tid = threadIdx.x;
  int w = tid >> 6;
  int lane = tid & 63;
  int l15 = lane & 15;
  int quad = lane >> 4;

  const short* Pp = Pbf + ((size_t)b * N_ + qb + w * 16 + l15) * N_ + quad * 8;
  const short* Vp = Vt + ((size_t)b * C_ + cb + l15) * N_ + quad * 8;

  f32x4 z = {0.f, 0.f, 0.f, 0.f};
  f32x4 acc[4] = {z, z, z, z};

#pragma unroll 4
  for (int ks = 0; ks < N_; ks += 32) {
    short8 a  = *(const short8*)(Pp + ks);
    short8 b0 = *(const short8*)(Vp + ks);
    short8 b1 = *(const short8*)(Vp + 16 * N_ + ks);
    short8 b2 = *(const short8*)(Vp + 32 * N_ + ks);
    short8 b3 = *(const short8*)(Vp + 48 * N_ + ks);
    acc[0] = __builtin_amdgcn_mfma_f32_16x16x32_bf16(a, b0, acc[0], 0, 0, 0);
    acc[1] = __builtin_amdgcn_mfma_f32_16x16x32_bf16(a, b1, acc[1], 0, 0, 0);
    acc[2] = __builtin_amdgcn_mfma_f32_16x16x32_bf16(a, b2, acc[2], 0, 0, 0);
    acc[3] = __builtin_amdgcn_mfma_f32_16x16x32_bf16(a, b3, acc[3], 0, 0, 0);
  }

  int q0 = qb + w * 16 + quad * 4;
#pragma unroll
  for (int t = 0; t < 4; t++) {
    int c = cb + t * 16 + l15;
#pragma unroll
    for (int r = 0; r < 4; r++) {
      O[((size_t)b * N_ + q0 + r) * C_ + c] = acc[t][r];
    }
  }
}

extern "C" void kernel_launch(void* const* d_in, const int* in_sizes, int n_in,
                              void* d_out, int out_size, void* d_ws, size_t ws_size,
                              hipStream_t stream) {
  const float* Q   = (const float*)d_in[0];
  const float* K   = (const float*)d_in[1];
  const float* V   = (const float*)d_in[2];
  const int* mask  = (const int*)d_in[3];
  const float* dis = (const float*)d_in[4];

  float* out = (float*)d_out;
  float* p_val  = out;                          // (B,N,C)
  float* p_attn = out + (size_t)B_ * N_ * C_;   // (B,N,N)

  short* Pbf = (short*)d_ws;                    // B*N*N bf16 = 32 MiB
  short* Vt  = Pbf + (size_t)B_ * N_ * N_;      // B*C*N bf16 = 8 MiB

  vt_kernel<<<dim3(N_ / 32, C_ / 32, B_), 256, 0, stream>>>(V, Vt);
  qk_kernel<<<dim3(N_ / 64, N_ / 64, B_), 256, 0, stream>>>(Q, K, dis, mask, p_attn);
  softmax_kernel<<<dim3(B_ * N_), 256, 0, stream>>>(p_attn, Pbf);
  pv_kernel<<<dim3(N_ / 64, C_ / 64, B_), 256, 0, stream>>>(Pbf, Vt, p_val);
}

// Round 2
// 335.097 us; speedup vs baseline: 1.2798x; 1.2798x over previous
//
#include <hip/hip_runtime.h>
#include <stdint.h>

#define B_ 16
#define N_ 1024
#define C_ 256

typedef __attribute__((ext_vector_type(8))) short short8;
typedef __attribute__((ext_vector_type(4))) float f32x4;

__device__ __forceinline__ short f2bf(float f) {
  uint32_t u = __builtin_bit_cast(uint32_t, f);
  u += 0x7fffu + ((u >> 16) & 1u);   // RNE to bf16
  return (short)(u >> 16);
}

// f32 -> bf16 elementwise, 8 elems/thread
__global__ __launch_bounds__(256) void cast_kernel(const float* __restrict__ in,
                                                   short* __restrict__ out, int n8) {
  int i = blockIdx.x * 256 + threadIdx.x;
  if (i >= n8) return;
  const float4* p = (const float4*)(in + (size_t)i * 8);
  float4 a = p[0], b = p[1];
  short8 r;
  r[0] = f2bf(a.x); r[1] = f2bf(a.y); r[2] = f2bf(a.z); r[3] = f2bf(a.w);
  r[4] = f2bf(b.x); r[5] = f2bf(b.y); r[6] = f2bf(b.z); r[7] = f2bf(b.w);
  *(short8*)(out + (size_t)i * 8) = r;
}

// V (B,N,C) f32 -> Vt (B,C,N) bf16
__global__ __launch_bounds__(256) void vt_kernel(const float* __restrict__ V,
                                                 short* __restrict__ Vt) {
  __shared__ float tile[32][33];
  int b = blockIdx.z;
  int nb = blockIdx.x * 32;
  int cb = blockIdx.y * 32;
  int tx = threadIdx.x & 31;
  int ty = threadIdx.x >> 5;
#pragma unroll
  for (int i = 0; i < 32; i += 8)
    tile[ty + i][tx] = V[((size_t)b * N_ + nb + ty + i) * C_ + cb + tx];
  __syncthreads();
#pragma unroll
  for (int i = 0; i < 32; i += 8)
    Vt[((size_t)b * C_ + cb + ty + i) * N_ + nb + tx] = f2bf(tile[tx][ty + i]);
}

// Fused: S = mask ? -inf : (Q K^T + dis)/16 ; softmax ; p_attn write ; PV ; p_val write
// Block: 16 q-rows of one batch, full k=1024. 4 waves, wave w owns k in [w*256, w*256+256).
__global__ __launch_bounds__(256, 2) void attn_kernel(
    const short* __restrict__ Qbf, const short* __restrict__ Kbf,
    const short* __restrict__ Vt, const float* __restrict__ dis,
    const int* __restrict__ mask, float* __restrict__ p_attn,
    float* __restrict__ p_val) {
  __shared__ short P_lds[16 * 1032];    // P in A-layout, padded stride
  __shared__ float red[4][4][4];        // [wave][quad][r]

  int gid = blockIdx.x;
  int b = (gid & 7) * 2 + ((gid >> 3) & 1);   // XCD-grouped batches
  int q0 = (gid >> 4) * 16;
  int tid = threadIdx.x;
  int w = tid >> 6;
  int lane = tid & 63;
  int l15 = lane & 15;
  int quad = lane >> 4;

  // ---------- QK^T into registers ----------
  f32x4 z = {0.f, 0.f, 0.f, 0.f};
  f32x4 acc[16];
#pragma unroll
  for (int i = 0; i < 16; i++) acc[i] = z;

  const short* Qp = Qbf + ((size_t)b * N_ + q0 + l15) * C_ + quad * 8;
  const short* Kp = Kbf + ((size_t)b * N_ + w * 256 + l15) * C_ + quad * 8;

#pragma unroll
  for (int cs = 0; cs < C_; cs += 32) {
    short8 a = *(const short8*)(Qp + cs);
#pragma unroll
    for (int kt = 0; kt < 16; kt++) {
      short8 bf = *(const short8*)(Kp + (size_t)kt * 16 * C_ + cs);
      acc[kt] = __builtin_amdgcn_mfma_f32_16x16x32_bf16(a, bf, acc[kt], 0, 0, 0);
    }
  }

  // ---------- + dis, mask, scale; row-max ----------
  size_t rb[4];
#pragma unroll
  for (int r = 0; r < 4; r++)
    rb[r] = ((size_t)b * N_ + q0 + quad * 4 + r) * N_ + w * 256 + l15;

  float s[16][4];
  float mrow[4] = {-1e30f, -1e30f, -1e30f, -1e30f};
#pragma unroll
  for (int kc = 0; kc < 4; kc++) {        // 4 chunks of 4 k-tiles: batched loads
    float dv[4][4];
    int mv[4][4];
#pragma unroll
    for (int k4 = 0; k4 < 4; k4++)
#pragma unroll
      for (int r = 0; r < 4; r++) {
        size_t idx = rb[r] + (size_t)(kc * 4 + k4) * 16;
        dv[k4][r] = dis[idx];
        mv[k4][r] = mask[idx];
      }
#pragma unroll
    for (int k4 = 0; k4 < 4; k4++)
#pragma unroll
      for (int r = 0; r < 4; r++) {
        int kt = kc * 4 + k4;
        float v = mv[k4][r] ? -3.0e38f : (acc[kt][r] + dv[k4][r]) * 0.0625f;
        s[kt][r] = v;
        mrow[r] = fmaxf(mrow[r], v);
      }
  }

  // intra-wave reduce over the 16 lanes holding each row
#pragma unroll
  for (int r = 0; r < 4; r++) {
    float m = mrow[r];
    m = fmaxf(m, __shfl_xor(m, 1));
    m = fmaxf(m, __shfl_xor(m, 2));
    m = fmaxf(m, __shfl_xor(m, 4));
    m = fmaxf(m, __shfl_xor(m, 8));
    mrow[r] = m;
  }
  if (l15 == 0) {
#pragma unroll
    for (int r = 0; r < 4; r++) red[w][quad][r] = mrow[r];
  }
  __syncthreads();
  float M[4];
#pragma unroll
  for (int r = 0; r < 4; r++)
    M[r] = fmaxf(fmaxf(red[0][quad][r], red[1][quad][r]),
                 fmaxf(red[2][quad][r], red[3][quad][r]));
  __syncthreads();   // before red reuse for sums

  // ---------- exp & row-sum ----------
  float lsum[4] = {0.f, 0.f, 0.f, 0.f};
#pragma unroll
  for (int kt = 0; kt < 16; kt++)
#pragma unroll
    for (int r = 0; r < 4; r++) {
      float e = __expf(s[kt][r] - M[r]);
      s[kt][r] = e;
      lsum[r] += e;
    }
#pragma unroll
  for (int r = 0; r < 4; r++) {
    float t = lsum[r];
    t += __shfl_xor(t, 1);
    t += __shfl_xor(t, 2);
    t += __shfl_xor(t, 4);
    t += __shfl_xor(t, 8);
    lsum[r] = t;
  }
  if (l15 == 0) {
#pragma unroll
    for (int r = 0; r < 4; r++) red[w][quad][r] = lsum[r];
  }
  __syncthreads();
  float inv[4];
#pragma unroll
  for (int r = 0; r < 4; r++) {
    float L = (red[0][quad][r] + red[1][quad][r]) +
              (red[2][quad][r] + red[3][quad][r]);
    inv[r] = 1.0f / L;
  }

  // ---------- write p_attn (f32) + P to LDS (bf16, A-layout) ----------
#pragma unroll
  for (int kt = 0; kt < 16; kt++)
#pragma unroll
    for (int r = 0; r < 4; r++) {
      float p = s[kt][r] * inv[r];
      p_attn[rb[r] + (size_t)kt * 16] = p;
      P_lds[(quad * 4 + r) * 1032 + w * 256 + kt * 16 + l15] = f2bf(p);
    }
  __syncthreads();

  // ---------- PV: out cols w*64 .. w*64+63 ----------
  f32x4 o[4];
#pragma unroll
  for (int i = 0; i < 4; i++) o[i] = z;
  const short* Vp = Vt + ((size_t)b * C_ + w * 64 + l15) * N_ + quad * 8;

#pragma unroll 4
  for (int ks = 0; ks < N_; ks += 32) {
    short8 a = *(const short8*)&P_lds[l15 * 1032 + ks + quad * 8];
#pragma unroll
    for (int ct = 0; ct < 4; ct++) {
      short8 bf = *(const short8*)(Vp + (size_t)ct * 16 * N_ + ks);
      o[ct] = __builtin_amdgcn_mfma_f32_16x16x32_bf16(a, bf, o[ct], 0, 0, 0);
    }
  }

#pragma unroll
  for (int ct = 0; ct < 4; ct++)
#pragma unroll
    for (int r = 0; r < 4; r++)
      p_val[((size_t)b * N_ + q0 + quad * 4 + r) * C_ + w * 64 + ct * 16 + l15] =
          o[ct][r];
}

extern "C" void kernel_launch(void* const* d_in, const int* in_sizes, int n_in,
                              void* d_out, int out_size, void* d_ws, size_t ws_size,
                              hipStream_t stream) {
  const float* Q   = (const float*)d_in[0];
  const float* K   = (const float*)d_in[1];
  const float* V   = (const float*)d_in[2];
  const int* mask  = (const int*)d_in[3];
  const float* dis = (const float*)d_in[4];

  float* out = (float*)d_out;
  float* p_val  = out;                          // (B,N,C)
  float* p_attn = out + (size_t)B_ * N_ * C_;   // (B,N,N)

  const size_t nelem = (size_t)B_ * N_ * C_;    // 4,194,304
  short* Qbf = (short*)d_ws;
  short* Kbf = Qbf + nelem;
  short* Vt  = Kbf + nelem;

  int n8 = (int)(nelem / 8);                    // 524288
  cast_kernel<<<dim3(n8 / 256), 256, 0, stream>>>(Q, Qbf, n8);
  cast_kernel<<<dim3(n8 / 256), 256, 0, stream>>>(K, Kbf, n8);
  vt_kernel<<<dim3(N_ / 32, C_ / 32, B_), 256, 0, stream>>>(V, Vt);
  attn_kernel<<<dim3(B_ * (N_ / 16)), 256, 0, stream>>>(Qbf, Kbf, Vt, dis, mask,
                                                        p_attn, p_val);
}